// Round 8
// baseline (398.136 us; speedup 1.0000x reference)
//
#include <hip/hip_runtime.h>

// NarrativeClassificationLoss — v8.
// Evidence R4/R5/R7: main time invariant at ~61 us whether 12 waves x 2-3
// loads in flight (R4) or 5 waves x 16 (R7) -> limiter is the PRODUCT
// waves*in-flight (VGPR landing-buffer bytes per CU), ~80 KB/CU in both.
// v8 raises the product ~2.5x: (256,5) -> 20 waves/CU at 8 loads in
// flight/wave, no spills (102-reg cap vs est ~90 use). RPB=16 halves
// table+reduce traffic.
//
// B=16384, N_NARR=128, N_SUB=1024, K=8, GAMMA=2, weights (1,1,0.5).

#define BDIM 256
#define NROWS 16384
#define NNARR 128
#define NSUB 1024
#define RPB 16
#define NBLOCKS (NROWS / RPB)      // 1024

// per-copy table layout (floats)
#define WS_AN    0      // [128]  sum_b y*sp(-x)            (narrative)
#define WS_CN    128    // [128]  sum_b (1-y)*sp(x)
#define WS_NSUM  256    // [128]  col sums of narrative labels
#define WS_AS    384    // [1024] sum_b pos*y*sp(-x)        (subnarrative)
#define WS_CS    1408   // [1024] sum_b pos*(1-y)*sp(x)
#define WS_SSUM  2432   // [1024] col sums of sub labels
#define WS_FN    3456   // focal narrative sum
#define WS_FS    3457   // focal subnarrative sum
#define WS_HIER  3458   // hierarchy sum
#define WS_FLOATS 3459
#define CSTRIDE  3472   // copy stride in floats (16B aligned)
#define CHUNK    64     // reduce1 fan-in
#define NTMP     16     // max chunk tables (1024/64)

__device__ __forceinline__ void bce_pieces(float x, float& sp_p, float& sp_m, float& sig) {
    float a = fabsf(x);
    float e = __expf(-a);              // exp(-|x|) in (0,1]
    float l = __logf(1.0f + e);        // ~log1p(e); err ~1e-7, fine after /2M
    sp_p = fmaxf(x, 0.0f) + l;
    sp_m = sp_p - x;
    float inv = __builtin_amdgcn_rcpf(1.0f + e);
    sig = (x >= 0.0f) ? inv : e * inv;
}

__device__ __forceinline__ void emit4(float* dst, float a, float b, float c, float d, int excl) {
    if (excl) {
        *(float4*)dst = make_float4(a, b, c, d);
    } else {
        atomicAdd(dst + 0, a); atomicAdd(dst + 1, b);
        atomicAdd(dst + 2, c); atomicAdd(dst + 3, d);
    }
}

// one sub row: 4 cols from (x4,y4), accumulate into As/Cs/ss/fs/hier
__device__ __forceinline__ void sub_row(const float4& x4, const int4& y4, float pv,
                                        int t, float* As, float* Cs, float* ss,
                                        float& fs, float& hier) {
    const float posv = (__float_as_uint(pv) >> 31) ? 0.0f : 1.0f;
    const float xv[4] = {x4.x, x4.y, x4.z, x4.w};
    const float yv[4] = {(float)y4.x, (float)y4.y, (float)y4.z, (float)y4.w};
    float mymax = 0.0f;
    #pragma unroll
    for (int j = 0; j < 4; ++j) {
        float sp_p, sp_m, sig;
        bce_pieces(xv[j], sp_p, sp_m, sig);
        float y  = yv[j];
        float ya = posv * y;
        As[j] += ya * sp_m;
        Cs[j] += (posv - ya) * sp_p;
        ss[j] += y;
        float om = 1.0f - sig;
        fs += om * om * y * (-sp_m);
        mymax = fmaxf(mymax, sig);
    }
    float gmax = fmaxf(mymax, __shfl_xor(mymax, 1, 64));
    if ((t & 1) == 0)
        hier += fmaxf(gmax - fabsf(pv), 0.0f) * posv;
}

__global__ __launch_bounds__(BDIM, 5) void ncl_main(
    const float* __restrict__ nlog, const float* __restrict__ slog,
    const int*   __restrict__ nlab, const int*   __restrict__ slab,
    float* __restrict__ ws, int ncopies, int excl)
{
    __shared__ float sred[BDIM][13];     // 13.3 KB narrative fold buffer
    __shared__ float pss_s[RPB * NNARR]; // 8 KB: sign bit = !pos, |v| = sigmoid
    __shared__ float ssc[4][3];          // per-wave scalar partials

    const int t  = threadIdx.x;
    const int r0 = blockIdx.x * RPB;
    float* const cw = ws + (size_t)(blockIdx.x % ncopies) * CSTRIDE;

    float fn = 0.f, fs = 0.f, hier = 0.f;

    // ---- narrative phase: 16 rows x 128 cols = 512 float4 quads ----
    // iter i: row i*8+(t>>5), col-quad t&31 (same quad both iters).
    {
        float An[4] = {0,0,0,0}, Cn[4] = {0,0,0,0}, ns[4] = {0,0,0,0};
        #pragma unroll
        for (int i = 0; i < 2; ++i) {
            const int base = r0 * NNARR + 4 * (i * BDIM + t);
            const float4 xs = *(const float4*)(nlog + base);
            const int4   ys = *(const int4*)  (nlab + base);
            const float xv[4] = {xs.x, xs.y, xs.z, xs.w};
            const float yv[4] = {(float)ys.x, (float)ys.y, (float)ys.z, (float)ys.w};
            float ps[4];
            #pragma unroll
            for (int j = 0; j < 4; ++j) {
                float sp_p, sp_m, sig;
                bce_pieces(xv[j], sp_p, sp_m, sig);
                float y = yv[j];
                An[j] += y * sp_m;
                Cn[j] += (1.0f - y) * sp_p;
                ns[j] += y;
                float om = 1.0f - sig;
                fn += om * om * y * (-sp_m);      // log_sigmoid(x) = -softplus(-x)
                ps[j] = (y != 0.0f) ? sig : -sig; // -0.0 keeps sign when sig==0
            }
            const int row = i * 8 + (t >> 5);
            *(float4*)&pss_s[row * NNARR + 4 * (t & 31)] =
                make_float4(ps[0], ps[1], ps[2], ps[3]);
        }
        #pragma unroll
        for (int j = 0; j < 4; ++j) {
            sred[t][j] = An[j]; sred[t][4 + j] = Cn[j]; sred[t][8 + j] = ns[j];
        }
    }
    __syncthreads();

    // ---- batch A loads: rows 0..7, straight-line, 16 loads in flight ----
    const float* sx = slog + (size_t)r0 * NSUB + 4 * t;
    const int*   sy = slab + (size_t)r0 * NSUB + 4 * t;
    float4 xa[8]; int4 ya[8];
    #pragma unroll
    for (int i = 0; i < 8; ++i) xa[i] = *(const float4*)(sx + (size_t)i * NSUB);
    #pragma unroll
    for (int i = 0; i < 8; ++i) ya[i] = *(const int4*)  (sy + (size_t)i * NSUB);

    // narrative fold overlaps batch-A latency (t<32 only)
    if (t < 32) {
        float a[12];
        #pragma unroll
        for (int j = 0; j < 12; ++j) a[j] = sred[t][j];
        #pragma unroll
        for (int s = 1; s < 8; ++s)
            #pragma unroll
            for (int j = 0; j < 12; ++j) a[j] += sred[t + 32 * s][j];
        emit4(cw + WS_AN   + 4 * t, a[0], a[1], a[2],  a[3],  excl);
        emit4(cw + WS_CN   + 4 * t, a[4], a[5], a[6],  a[7],  excl);
        emit4(cw + WS_NSUM + 4 * t, a[8], a[9], a[10], a[11], excl);
    }

    // ---- compute batch A ----
    const int g = t >> 1;
    float As[4] = {0,0,0,0}, Cs[4] = {0,0,0,0}, ss[4] = {0,0,0,0};
    #pragma unroll
    for (int i = 0; i < 8; ++i)
        sub_row(xa[i], ya[i], pss_s[i * NNARR + g], t, As, Cs, ss, fs, hier);

    // ---- batch B loads: rows 8..15 ----
    float4 xb[8]; int4 yb[8];
    #pragma unroll
    for (int i = 0; i < 8; ++i) xb[i] = *(const float4*)(sx + (size_t)(8 + i) * NSUB);
    #pragma unroll
    for (int i = 0; i < 8; ++i) yb[i] = *(const int4*)  (sy + (size_t)(8 + i) * NSUB);

    // ---- compute batch B ----
    #pragma unroll
    for (int i = 0; i < 8; ++i)
        sub_row(xb[i], yb[i], pss_s[(8 + i) * NNARR + g], t, As, Cs, ss, fs, hier);

    // thread t uniquely owns its 4 sub cols within the block: direct store
    emit4(cw + WS_AS   + 4 * t, As[0], As[1], As[2], As[3], excl);
    emit4(cw + WS_CS   + 4 * t, Cs[0], Cs[1], Cs[2], Cs[3], excl);
    emit4(cw + WS_SSUM + 4 * t, ss[0], ss[1], ss[2], ss[3], excl);

    // scalar partials: wave shuffle reduce -> LDS -> thread 0
    #pragma unroll
    for (int off = 32; off; off >>= 1) {
        fn   += __shfl_down(fn,   off, 64);
        fs   += __shfl_down(fs,   off, 64);
        hier += __shfl_down(hier, off, 64);
    }
    if ((t & 63) == 0) {
        int w = t >> 6;
        ssc[w][0] = fn; ssc[w][1] = fs; ssc[w][2] = hier;
    }
    __syncthreads();
    if (t == 0) {
        float a = 0.f, b = 0.f, c = 0.f;
        #pragma unroll
        for (int w = 0; w < 4; ++w) { a += ssc[w][0]; b += ssc[w][1]; c += ssc[w][2]; }
        if (excl) {
            cw[WS_FN] = a; cw[WS_FS] = b; cw[WS_HIER] = c;
        } else {
            atomicAdd(cw + WS_FN, a); atomicAdd(cw + WS_FS, b); atomicAdd(cw + WS_HIER, c);
        }
    }
}

// reduce stage 1: chunk cb sums copies [cb*CHUNK, ...) -> tmp[cb], float4-wide
__global__ __launch_bounds__(256) void ncl_reduce1(const float* __restrict__ ws,
                                                   float* __restrict__ tmp,
                                                   int ncopies)
{
    const int e4 = blockIdx.x * 256 + threadIdx.x;
    if (e4 >= CSTRIDE / 4) return;
    const int c0 = blockIdx.y * CHUNK;
    const int c1 = min(c0 + CHUNK, ncopies);
    float4 s = make_float4(0.f, 0.f, 0.f, 0.f);
    for (int c = c0; c < c1; ++c) {
        float4 v = *(const float4*)(ws + (size_t)c * CSTRIDE + 4 * e4);
        s.x += v.x; s.y += v.y; s.z += v.z; s.w += v.w;
    }
    *(float4*)(tmp + (size_t)blockIdx.y * CSTRIDE + 4 * e4) = s;
}

// fused reduce2 + finalize: single block, 1024 threads
__global__ __launch_bounds__(1024) void ncl_final(const float* __restrict__ tmp,
                                                  float* __restrict__ out, int nchunks)
{
    __shared__ float sr[3][16];
    __shared__ float sc3[3];
    const int t = threadIdx.x;
    const float Bf = (float)NROWS;

    float s_as = 0.f, s_cs = 0.f, s_ss = 0.f;
    #pragma unroll 4
    for (int c = 0; c < nchunks; ++c) {
        const float* b = tmp + (size_t)c * CSTRIDE;
        s_as += b[WS_AS + t]; s_cs += b[WS_CS + t]; s_ss += b[WS_SSUM + t];
    }
    float s_an = 0.f, s_cn = 0.f, s_ns = 0.f;
    if (t < NNARR) {
        #pragma unroll 4
        for (int c = 0; c < nchunks; ++c) {
            const float* b = tmp + (size_t)c * CSTRIDE;
            s_an += b[WS_AN + t]; s_cn += b[WS_CN + t]; s_ns += b[WS_NSUM + t];
        }
    }
    if (t < 3) {
        float s = 0.f;
        for (int c = 0; c < nchunks; ++c) s += tmp[(size_t)c * CSTRIDE + WS_FN + t];
        sc3[t] = s;
    }

    float spw = fminf(fmaxf((Bf - s_ss) / (s_ss + 1e-6f), 1.0f), 50.0f);
    float sub_part = spw * s_as + s_cs;
    float narr_part = 0.f, valid_part = 0.f;
    if (t < NNARR) {
        float npw = fminf(fmaxf((Bf - s_ns) / (s_ns + 1e-6f), 1.0f), 50.0f);
        narr_part  = npw * s_an + s_cn;
        valid_part = s_ns;
    }

    #pragma unroll
    for (int off = 32; off; off >>= 1) {
        sub_part   += __shfl_down(sub_part,   off, 64);
        narr_part  += __shfl_down(narr_part,  off, 64);
        valid_part += __shfl_down(valid_part, off, 64);
    }
    if ((t & 63) == 0) {
        int w = t >> 6;
        sr[0][w] = sub_part; sr[1][w] = narr_part; sr[2][w] = valid_part;
    }
    __syncthreads();
    if (t == 0) {
        float sub_tot = 0.f, narr_tot = 0.f, valid = 0.f;
        #pragma unroll
        for (int i = 0; i < 16; ++i) { sub_tot += sr[0][i]; narr_tot += sr[1][i]; valid += sr[2][i]; }

        float narrative_loss = narr_tot / (Bf * (float)NNARR);
        float sub_loss = (valid > 0.0f) ? (sub_tot * (1.0f / 8.0f)) / fmaxf(valid, 1.0f) : 0.0f;
        float nf = sc3[0] / (Bf * (float)NNARR);
        float sf = sc3[1] / (Bf * (float)NSUB);
        float hier_loss = sc3[2] / Bf;

        out[0] = (narrative_loss - 0.1f * nf)
               + (sub_loss       - 0.1f * sf)
               + 0.5f * hier_loss;
    }
}

extern "C" void kernel_launch(void* const* d_in, const int* in_sizes, int n_in,
                              void* d_out, int out_size, void* d_ws, size_t ws_size,
                              hipStream_t stream) {
    const float* nlog = (const float*)d_in[0];
    const float* slog = (const float*)d_in[1];
    const int*   nlab = (const int*)d_in[2];
    const int*   slab = (const int*)d_in[3];
    float* ws  = (float*)d_ws;
    float* out = (float*)d_out;

    // ws layout: [ncopies copies][NTMP chunk tables]
    long avail = (long)(ws_size / 4);
    long nc = avail / CSTRIDE - NTMP;
    int ncopies = (int)(nc < 1 ? 1 : (nc > NBLOCKS ? NBLOCKS : nc));
    int excl = (ncopies == NBLOCKS) ? 1 : 0;
    float* tmp = (nc < 1) ? ws : ws + (size_t)ncopies * CSTRIDE;
    int nchunks = (ncopies + CHUNK - 1) / CHUNK;

    if (!excl)
        hipMemsetAsync(ws, 0, (size_t)ncopies * CSTRIDE * sizeof(float), stream);

    ncl_main<<<NBLOCKS, BDIM, 0, stream>>>(nlog, slog, nlab, slab, ws, ncopies, excl);

    dim3 g1((CSTRIDE / 4 + 255) / 256, nchunks);
    ncl_reduce1<<<g1, 256, 0, stream>>>(ws, tmp, ncopies);
    ncl_final<<<1, 1024, 0, stream>>>(tmp, out, nchunks);
}

// Round 9
// 201.940 us; speedup vs baseline: 1.9716x; 1.9716x over previous
//
#include <hip/hip_runtime.h>

// NarrativeClassificationLoss — v9.
// R8 post-mortem: launch_bounds(256,5) -> allocator overshot to 48 VGPR,
// spilled the prefetch buffers (349/469 MB scratch traffic). Allocator is
// only sane at waves-per-eu = 2 or 4 (R7: 116 regs, R4: 60 regs, no spill).
// R8 also showed 3.27 TB/s sustained by this shape -> 61 us is NOT a BW
// wall. The clean high-occupancy test (no spills) has never run: v9 = v5's
// lean body (compiled to 32 VGPR under a 64 cap) at (256,4) -> expect
// ~50-64 VGPR, no spill, 8 blocks/CU = up to 32 waves/CU.
//
// B=16384, N_NARR=128, N_SUB=1024, K=8, GAMMA=2, weights (1,1,0.5).

#define BDIM 256
#define NROWS 16384
#define NNARR 128
#define NSUB 1024
#define RPB 8
#define NBLOCKS (NROWS / RPB)      // 2048

// per-copy table layout (floats)
#define WS_AN    0      // [128]  sum_b y*sp(-x)            (narrative)
#define WS_CN    128    // [128]  sum_b (1-y)*sp(x)
#define WS_NSUM  256    // [128]  col sums of narrative labels
#define WS_AS    384    // [1024] sum_b pos*y*sp(-x)        (subnarrative)
#define WS_CS    1408   // [1024] sum_b pos*(1-y)*sp(x)
#define WS_SSUM  2432   // [1024] col sums of sub labels
#define WS_FN    3456   // focal narrative sum
#define WS_FS    3457   // focal subnarrative sum
#define WS_HIER  3458   // hierarchy sum
#define WS_FLOATS 3459
#define CSTRIDE  3472   // copy stride in floats (16B aligned)
#define CHUNK    64     // reduce1 fan-in
#define NTMP     32     // max chunk tables (2048/64)

__device__ __forceinline__ void bce_pieces(float x, float& sp_p, float& sp_m, float& sig) {
    float a = fabsf(x);
    float e = __expf(-a);              // exp(-|x|) in (0,1]
    float l = __logf(1.0f + e);        // ~log1p(e); err ~1e-7, fine after /2M
    sp_p = fmaxf(x, 0.0f) + l;
    sp_m = sp_p - x;
    float inv = __builtin_amdgcn_rcpf(1.0f + e);
    sig = (x >= 0.0f) ? inv : e * inv;
}

__device__ __forceinline__ void emit4(float* dst, float a, float b, float c, float d, int excl) {
    if (excl) {
        *(float4*)dst = make_float4(a, b, c, d);
    } else {
        atomicAdd(dst + 0, a); atomicAdd(dst + 1, b);
        atomicAdd(dst + 2, c); atomicAdd(dst + 3, d);
    }
}

__global__ __launch_bounds__(BDIM, 4) void ncl_main(
    const float* __restrict__ nlog, const float* __restrict__ slog,
    const int*   __restrict__ nlab, const int*   __restrict__ slab,
    float* __restrict__ ws, int ncopies, int excl)
{
    __shared__ float sred[BDIM][13];     // 13.3 KB narrative fold buffer
    __shared__ float pss_s[RPB * NNARR]; // 4 KB: sign bit = !pos, |v| = sigmoid
    __shared__ float ssc[4][3];          // per-wave scalar partials

    const int t  = threadIdx.x;
    const int r0 = blockIdx.x * RPB;
    float* const cw = ws + (size_t)(blockIdx.x % ncopies) * CSTRIDE;

    float fn = 0.f, fs = 0.f, hier = 0.f;

    // ---- narrative phase: 8 rows x 128 cols, one float4 quad per thread ----
    // thread t: row = t>>5, cols 4*(t&31)..+3.
    {
        const int base = r0 * NNARR + 4 * t;
        const float4 xs = *(const float4*)(nlog + base);
        const int4   ys = *(const int4*)  (nlab + base);
        const float xv[4] = {xs.x, xs.y, xs.z, xs.w};
        const float yv[4] = {(float)ys.x, (float)ys.y, (float)ys.z, (float)ys.w};
        float An[4], Cn[4], ns[4], ps[4];
        #pragma unroll
        for (int j = 0; j < 4; ++j) {
            float sp_p, sp_m, sig;
            bce_pieces(xv[j], sp_p, sp_m, sig);
            float y = yv[j];
            An[j] = y * sp_m;
            Cn[j] = (1.0f - y) * sp_p;
            ns[j] = y;
            float om = 1.0f - sig;
            fn += om * om * y * (-sp_m);        // log_sigmoid(x) = -softplus(-x)
            ps[j] = (y != 0.0f) ? sig : -sig;   // -0.0 keeps sign when sig==0
        }
        *(float4*)&pss_s[(t >> 5) * NNARR + 4 * (t & 31)] =
            make_float4(ps[0], ps[1], ps[2], ps[3]);
        #pragma unroll
        for (int j = 0; j < 4; ++j) {
            sred[t][j] = An[j]; sred[t][4 + j] = Cn[j]; sred[t][8 + j] = ns[j];
        }
    }
    __syncthreads();
    if (t < 32) {   // fold 8 threads per col-quad (t, t+32, ..., t+224)
        float a[12];
        #pragma unroll
        for (int j = 0; j < 12; ++j) a[j] = sred[t][j];
        #pragma unroll
        for (int s = 1; s < 8; ++s)
            #pragma unroll
            for (int j = 0; j < 12; ++j) a[j] += sred[t + 32 * s][j];
        emit4(cw + WS_AN   + 4 * t, a[0], a[1], a[2],  a[3],  excl);
        emit4(cw + WS_CN   + 4 * t, a[4], a[5], a[6],  a[7],  excl);
        emit4(cw + WS_NSUM + 4 * t, a[8], a[9], a[10], a[11], excl);
    }

    // ---- sub phase: 8 rows; thread owns cols 4t..4t+3 (group g = t>>1) ----
    const int g = t >> 1;
    float As[4] = {0,0,0,0}, Cs[4] = {0,0,0,0}, ss[4] = {0,0,0,0};
    #pragma unroll 4
    for (int i = 0; i < RPB; ++i) {
        const int r = r0 + i;
        const float  pv   = pss_s[i * NNARR + g];   // 2-lane LDS broadcast
        const float  posv = (__float_as_uint(pv) >> 31) ? 0.0f : 1.0f;
        const float4 xs = *(const float4*)(slog + (size_t)r * NSUB + 4 * t);
        const int4   ys = *(const int4*)  (slab + (size_t)r * NSUB + 4 * t);

        const float xv[4] = {xs.x, xs.y, xs.z, xs.w};
        const float yv[4] = {(float)ys.x, (float)ys.y, (float)ys.z, (float)ys.w};
        float mymax = 0.0f;
        #pragma unroll
        for (int j = 0; j < 4; ++j) {
            float sp_p, sp_m, sig;
            bce_pieces(xv[j], sp_p, sp_m, sig);
            float y  = yv[j];
            float ya = posv * y;
            As[j] += ya * sp_m;
            Cs[j] += (posv - ya) * sp_p;
            ss[j] += y;
            float om = 1.0f - sig;
            fs += om * om * y * (-sp_m);
            mymax = fmaxf(mymax, sig);
        }
        // group max over 8 cols = adjacent lane pair
        float gmax = fmaxf(mymax, __shfl_xor(mymax, 1, 64));
        if ((t & 1) == 0)
            hier += fmaxf(gmax - fabsf(pv), 0.0f) * posv;
    }

    // thread t uniquely owns its 4 sub cols within the block: direct store
    emit4(cw + WS_AS   + 4 * t, As[0], As[1], As[2], As[3], excl);
    emit4(cw + WS_CS   + 4 * t, Cs[0], Cs[1], Cs[2], Cs[3], excl);
    emit4(cw + WS_SSUM + 4 * t, ss[0], ss[1], ss[2], ss[3], excl);

    // scalar partials: wave shuffle reduce -> LDS -> thread 0
    #pragma unroll
    for (int off = 32; off; off >>= 1) {
        fn   += __shfl_down(fn,   off, 64);
        fs   += __shfl_down(fs,   off, 64);
        hier += __shfl_down(hier, off, 64);
    }
    if ((t & 63) == 0) {
        int w = t >> 6;
        ssc[w][0] = fn; ssc[w][1] = fs; ssc[w][2] = hier;
    }
    __syncthreads();
    if (t == 0) {
        float a = 0.f, b = 0.f, c = 0.f;
        #pragma unroll
        for (int w = 0; w < 4; ++w) { a += ssc[w][0]; b += ssc[w][1]; c += ssc[w][2]; }
        if (excl) {
            cw[WS_FN] = a; cw[WS_FS] = b; cw[WS_HIER] = c;
        } else {
            atomicAdd(cw + WS_FN, a); atomicAdd(cw + WS_FS, b); atomicAdd(cw + WS_HIER, c);
        }
    }
}

// reduce stage 1: chunk cb sums copies [cb*CHUNK, ...) -> tmp[cb], float4-wide
__global__ __launch_bounds__(256) void ncl_reduce1(const float* __restrict__ ws,
                                                   float* __restrict__ tmp,
                                                   int ncopies)
{
    const int e4 = blockIdx.x * 256 + threadIdx.x;
    if (e4 >= CSTRIDE / 4) return;
    const int c0 = blockIdx.y * CHUNK;
    const int c1 = min(c0 + CHUNK, ncopies);
    float4 s = make_float4(0.f, 0.f, 0.f, 0.f);
    for (int c = c0; c < c1; ++c) {
        float4 v = *(const float4*)(ws + (size_t)c * CSTRIDE + 4 * e4);
        s.x += v.x; s.y += v.y; s.z += v.z; s.w += v.w;
    }
    *(float4*)(tmp + (size_t)blockIdx.y * CSTRIDE + 4 * e4) = s;
}

// fused reduce2 + finalize: single block, 1024 threads
__global__ __launch_bounds__(1024) void ncl_final(const float* __restrict__ tmp,
                                                  float* __restrict__ out, int nchunks)
{
    __shared__ float sr[3][16];
    __shared__ float sc3[3];
    const int t = threadIdx.x;
    const float Bf = (float)NROWS;

    float s_as = 0.f, s_cs = 0.f, s_ss = 0.f;
    #pragma unroll 4
    for (int c = 0; c < nchunks; ++c) {
        const float* b = tmp + (size_t)c * CSTRIDE;
        s_as += b[WS_AS + t]; s_cs += b[WS_CS + t]; s_ss += b[WS_SSUM + t];
    }
    float s_an = 0.f, s_cn = 0.f, s_ns = 0.f;
    if (t < NNARR) {
        #pragma unroll 4
        for (int c = 0; c < nchunks; ++c) {
            const float* b = tmp + (size_t)c * CSTRIDE;
            s_an += b[WS_AN + t]; s_cn += b[WS_CN + t]; s_ns += b[WS_NSUM + t];
        }
    }
    if (t < 3) {
        float s = 0.f;
        for (int c = 0; c < nchunks; ++c) s += tmp[(size_t)c * CSTRIDE + WS_FN + t];
        sc3[t] = s;
    }

    float spw = fminf(fmaxf((Bf - s_ss) / (s_ss + 1e-6f), 1.0f), 50.0f);
    float sub_part = spw * s_as + s_cs;
    float narr_part = 0.f, valid_part = 0.f;
    if (t < NNARR) {
        float npw = fminf(fmaxf((Bf - s_ns) / (s_ns + 1e-6f), 1.0f), 50.0f);
        narr_part  = npw * s_an + s_cn;
        valid_part = s_ns;
    }

    #pragma unroll
    for (int off = 32; off; off >>= 1) {
        sub_part   += __shfl_down(sub_part,   off, 64);
        narr_part  += __shfl_down(narr_part,  off, 64);
        valid_part += __shfl_down(valid_part, off, 64);
    }
    if ((t & 63) == 0) {
        int w = t >> 6;
        sr[0][w] = sub_part; sr[1][w] = narr_part; sr[2][w] = valid_part;
    }
    __syncthreads();
    if (t == 0) {
        float sub_tot = 0.f, narr_tot = 0.f, valid = 0.f;
        #pragma unroll
        for (int i = 0; i < 16; ++i) { sub_tot += sr[0][i]; narr_tot += sr[1][i]; valid += sr[2][i]; }

        float narrative_loss = narr_tot / (Bf * (float)NNARR);
        float sub_loss = (valid > 0.0f) ? (sub_tot * (1.0f / 8.0f)) / fmaxf(valid, 1.0f) : 0.0f;
        float nf = sc3[0] / (Bf * (float)NNARR);
        float sf = sc3[1] / (Bf * (float)NSUB);
        float hier_loss = sc3[2] / Bf;

        out[0] = (narrative_loss - 0.1f * nf)
               + (sub_loss       - 0.1f * sf)
               + 0.5f * hier_loss;
    }
}

extern "C" void kernel_launch(void* const* d_in, const int* in_sizes, int n_in,
                              void* d_out, int out_size, void* d_ws, size_t ws_size,
                              hipStream_t stream) {
    const float* nlog = (const float*)d_in[0];
    const float* slog = (const float*)d_in[1];
    const int*   nlab = (const int*)d_in[2];
    const int*   slab = (const int*)d_in[3];
    float* ws  = (float*)d_ws;
    float* out = (float*)d_out;

    // ws layout: [ncopies copies][NTMP chunk tables]
    long avail = (long)(ws_size / 4);
    long nc = avail / CSTRIDE - NTMP;
    int ncopies = (int)(nc < 1 ? 1 : (nc > NBLOCKS ? NBLOCKS : nc));
    int excl = (ncopies == NBLOCKS) ? 1 : 0;
    float* tmp = (nc < 1) ? ws : ws + (size_t)ncopies * CSTRIDE;
    int nchunks = (ncopies + CHUNK - 1) / CHUNK;

    if (!excl)
        hipMemsetAsync(ws, 0, (size_t)ncopies * CSTRIDE * sizeof(float), stream);

    ncl_main<<<NBLOCKS, BDIM, 0, stream>>>(nlog, slog, nlab, slab, ws, ncopies, excl);

    dim3 g1((CSTRIDE / 4 + 255) / 256, nchunks);
    ncl_reduce1<<<g1, 256, 0, stream>>>(ws, tmp, ncopies);
    ncl_final<<<1, 1024, 0, stream>>>(tmp, out, nchunks);
}